// Round 4
// baseline (248.196 us; speedup 1.0000x reference)
//
#include <hip/hip_runtime.h>
#include <hip/hip_bf16.h>
#include <math.h>

// Shapes: B=2, Le=250, Ld=150, N=400, Wl=16, Vin=128, E=64, F=128, K=5
//         H=8, hid=32, d=256, Vout=5000
// Inputs fp32 (round-1 NaN proves bf16-misread; npz size > bf16 raw).
// OUTPUT fp32: reference returns float32; harness allocates d_out per the
// reference's output dtype. Round-0's "bf16-clean max|ref|" was the expected
// npz being stored bf16 — not evidence about the device buffer. Rounds 2/3
// (bf16 writes into the fp32 buffer) produced exactly the interleaved-pair
// error signature (0.117 > max|ref|).
// fixed_graph (in[2]) and dg_* (in[8..14]) are dead: adj=clip(sigmoid+fixed,0,1)
// is strictly positive, so the adjacency mask never fires (unmasked softmax).

// ---------- K0: T[k5][v][f] = sum_e emb[v][e] * convw[f][e][k5]
__global__ void k_table(const float* emb, const float* convw, float* T) {
    int v = blockIdx.x, f = threadIdx.x;          // grid 128, block 128
    __shared__ float er[64];
    if (f < 64) er[f] = emb[v * 64 + f];
    __syncthreads();
    float acc[5] = {0.f, 0.f, 0.f, 0.f, 0.f};
    const float* w = convw + f * 320;             // convw[f][e][k5]
    for (int e = 0; e < 64; ++e) {
        float xe = er[e];
#pragma unroll
        for (int k = 0; k < 5; ++k) acc[k] += xe * w[e * 5 + k];
    }
#pragma unroll
    for (int k = 0; k < 5; ++k) T[(k * 128 + v) * 128 + f] = acc[k];
}

// ---------- K1: char conv via table + bias + relu + maxpool -> xc[800][128]
__global__ void k_conv(const int* enc, const int* dec, const float* convb,
                       const float* T, float* xc) {
    int w = blockIdx.x;                            // grid 800, block 128
    int b = w / 400, n = w % 400;
    __shared__ int ids[16];
    int f = threadIdx.x;
    if (f < 16) {
        ids[f] = (n < 250) ? enc[(b * 250 + n) * 16 + f]
                           : dec[(b * 150 + (n - 250)) * 16 + f];
    }
    __syncthreads();
    float best = -1e30f;
    for (int p = 0; p < 16; ++p) {
        float s = 0.f;
#pragma unroll
        for (int k = 0; k < 5; ++k) {
            int q = p + k - 2;
            if (q >= 0 && q < 16) s += T[(k * 128 + ids[q]) * 128 + f];
        }
        best = fmaxf(best, s);
    }
    xc[w * 128 + f] = fmaxf(best + convb[f], 0.f);
}

// ---------- K2: x = xc @ hstW + hstb -> [800][256]
__global__ void k_hst(const float* xc, const float* W, const float* bias, float* x) {
    int w = blockIdx.x, t = threadIdx.x;           // grid 800, block 256
    __shared__ float xr[128];
    if (t < 128) xr[t] = xc[w * 128 + t];
    __syncthreads();
    float acc = bias[t];
    for (int c = 0; c < 128; ++c) acc += xr[c] * W[c * 256 + t];
    x[w * 256 + t] = acc;
}

// ---------- K3: Wh[b*8+h][n][k] = sum_d x[b,n,d] * attW[h][d][k]
__global__ void k_wh(const float* x, const float* attW, float* Wh) {
    int w = blockIdx.x, t = threadIdx.x;           // grid 800, block 256
    int h = t >> 5, k = t & 31;
    __shared__ float xr[256];
    xr[t] = x[w * 256 + t];
    __syncthreads();
    const float* Wp = attW + h * 8192 + k;
    float acc = 0.f;
    for (int d = 0; d < 256; ++d) acc += xr[d] * Wp[d * 32];
    int b = w / 400, n = w % 400;
    Wh[((b * 8 + h) * 400 + n) * 32 + k] = acc;
}

// ---------- K4: f1/f2 from staged Wh, unmasked softmax over m, PV, elu
#define WST 33
__global__ __launch_bounds__(256) void k_attn(const float* Wh, const float* a1g,
                                              const float* a2g, float* xout) {
    int tile = blockIdx.x, bh = blockIdx.y;        // grid (16 tiles, 16 bh)
    int b = bh >> 3, h = bh & 7;
    int t = threadIdx.x;
    __shared__ float Whl[400 * WST];
    __shared__ float f2l[400];
    __shared__ float pl[400];
    __shared__ float f1l[32];
    __shared__ float a1l[32], a2l[32];
    __shared__ float red[8][32];
    __shared__ float sred[4], wmax[4];

    const float* Whg = Wh + bh * 12800;
    for (int i = t; i < 12800; i += 256)
        Whl[(i >> 5) * WST + (i & 31)] = Whg[i];
    if (t < 32) { a1l[t] = a1g[h * 32 + t]; a2l[t] = a2g[h * 32 + t]; }
    __syncthreads();

    for (int m = t; m < 400; m += 256) {
        float s2 = 0.f;
        for (int k = 0; k < 32; ++k) s2 += Whl[m * WST + k] * a2l[k];
        f2l[m] = s2;
    }
    if (t < 25) {
        int n = tile * 25 + t;
        float s1 = 0.f;
        for (int k = 0; k < 32; ++k) s1 += Whl[n * WST + k] * a1l[k];
        f1l[t] = s1;
    }
    __syncthreads();

    // max_m f2  (leaky is monotone: rowmax = leaky(f1n + fmax2))
    float fm = -1e30f;
    for (int m = t; m < 400; m += 256) fm = fmaxf(fm, f2l[m]);
#pragma unroll
    for (int mm = 32; mm >= 1; mm >>= 1) fm = fmaxf(fm, __shfl_xor(fm, mm, 64));
    if ((t & 63) == 0) wmax[t >> 6] = fm;
    __syncthreads();
    float fmax2 = fmaxf(fmaxf(wmax[0], wmax[1]), fmaxf(wmax[2], wmax[3]));

    int kk = t & 31, g = t >> 5;
    for (int r = 0; r < 25; ++r) {
        int n = tile * 25 + r;
        float f1n = f1l[r];
        float rowm = f1n + fmax2;
        rowm = rowm > 0.f ? rowm : 0.2f * rowm;
        float ps = 0.f;
        for (int m = t; m < 400; m += 256) {
            float e = f1n + f2l[m];
            e = e > 0.f ? e : 0.2f * e;
            float p = __expf(e - rowm);
            pl[m] = p;
            ps += p;
        }
#pragma unroll
        for (int mm = 32; mm >= 1; mm >>= 1) ps += __shfl_xor(ps, mm, 64);
        if ((t & 63) == 0) sred[t >> 6] = ps;
        __syncthreads();
        float s = sred[0] + sred[1] + sred[2] + sred[3];
        float acc = 0.f;
        for (int m = g; m < 400; m += 8) acc += pl[m] * Whl[m * WST + kk];
        red[g][kk] = acc;
        __syncthreads();
        if (t < 32) {
            float o = 0.f;
#pragma unroll
            for (int j = 0; j < 8; ++j) o += red[j][t];
            o /= s;
            o = o > 0.f ? o : (__expf(o) - 1.f);   // elu
            xout[(b * 400 + n) * 256 + h * 32 + t] = o;
        }
        __syncthreads();
    }
}

// ---------- K5: out[r][v] = sum_d x[b, 250+dn, d]*W[d][v] + b[v]  (fp32 out)
__global__ void k_out(const float* x, const float* W, const float* bias,
                      float* out) {
    int vt = blockIdx.x, rg = blockIdx.y, t = threadIdx.x;  // grid (20, 12), block 256
    __shared__ float xr[25][256];
    int r0 = rg * 25;                              // 150%25==0: never crosses b
    int b = r0 / 150, n0 = 250 + (r0 % 150);
    for (int i = t; i < 6400; i += 256) {
        int rr = i >> 8, dd = i & 255;
        xr[rr][dd] = x[(b * 400 + n0 + rr) * 256 + dd];
    }
    __syncthreads();
    if (t >= 250) return;
    int v = vt * 250 + t;
    float acc[25];
#pragma unroll
    for (int rr = 0; rr < 25; ++rr) acc[rr] = 0.f;
    for (int dd = 0; dd < 256; ++dd) {
        float wv = W[dd * 5000 + v];
#pragma unroll
        for (int rr = 0; rr < 25; ++rr) acc[rr] += xr[rr][dd] * wv;
    }
    float bv = bias[v];
#pragma unroll
    for (int rr = 0; rr < 25; ++rr)
        out[(r0 + rr) * 5000 + v] = acc[rr] + bv;
}

extern "C" void kernel_launch(void* const* d_in, const int* in_sizes, int n_in,
                              void* d_out, int out_size, void* d_ws, size_t ws_size,
                              hipStream_t stream) {
    const int*   enc   = (const int*)d_in[0];
    const int*   dec   = (const int*)d_in[1];
    const float* emb   = (const float*)d_in[3];
    const float* convw = (const float*)d_in[4];
    const float* convb = (const float*)d_in[5];
    const float* hstW  = (const float*)d_in[6];
    const float* hstb  = (const float*)d_in[7];
    const float* attW  = (const float*)d_in[15];
    const float* a1    = (const float*)d_in[16];
    const float* a2    = (const float*)d_in[17];
    const float* outW  = (const float*)d_in[18];
    const float* outb  = (const float*)d_in[19];
    float* out = (float*)d_out;

    char* ws = (char*)d_ws;
    float* T   = (float*)ws; ws += 5 * 128 * 128 * 4;
    float* xc  = (float*)ws; ws += 800 * 128 * 4;
    float* xA  = (float*)ws; ws += 800 * 256 * 4;
    float* xB  = (float*)ws; ws += 800 * 256 * 4;
    float* Wh  = (float*)ws; ws += 16 * 400 * 32 * 4;

    k_table<<<128, 128, 0, stream>>>(emb, convw, T);
    k_conv<<<800, 128, 0, stream>>>(enc, dec, convb, T, xc);
    k_hst<<<800, 256, 0, stream>>>(xc, hstW, hstb, xA);

    float* xin = xA;
    float* xo  = xB;
    for (int it = 0; it < 2; ++it) {
        k_wh<<<800, 256, 0, stream>>>(xin, attW, Wh);
        k_attn<<<dim3(16, 16), 256, 0, stream>>>(Wh, a1, a2, xo);
        float* tmp = xin; xin = xo; xo = tmp;
    }
    k_out<<<dim3(20, 12), 256, 0, stream>>>(xin, outW, outb, out);
}

// Round 5
// 219.144 us; speedup vs baseline: 1.1326x; 1.1326x over previous
//
#include <hip/hip_runtime.h>
#include <hip/hip_bf16.h>
#include <math.h>

// Shapes: B=2, Le=250, Ld=150, N=400, Wl=16, Vin=128, E=64, F=128, K=5
//         H=8, hid=32, d=256, Vout=5000
// Inputs fp32, output fp32 (verified round 4: absmax 6e-5 pass).
// fixed_graph (in[2]) and dg_* (in[8..14]) are dead: adj=clip(sigmoid+fixed,0,1)
// is strictly positive => adjacency mask never fires (unmasked softmax).

// ---------- K0: T[k5][v][f] = sum_e emb[v][e] * convw[f][e][k5]
__global__ void k_table(const float* emb, const float* convw, float* T) {
    int v = blockIdx.x, f = threadIdx.x;          // grid 128, block 128
    __shared__ float er[64];
    if (f < 64) er[f] = emb[v * 64 + f];
    __syncthreads();
    float acc[5] = {0.f, 0.f, 0.f, 0.f, 0.f};
    const float* w = convw + f * 320;             // convw[f][e][k5]
    for (int e = 0; e < 64; ++e) {
        float xe = er[e];
#pragma unroll
        for (int k = 0; k < 5; ++k) acc[k] += xe * w[e * 5 + k];
    }
#pragma unroll
    for (int k = 0; k < 5; ++k) T[(k * 128 + v) * 128 + f] = acc[k];
}

// ---------- K1: char conv via table + bias + relu + maxpool -> xc[800][128]
__global__ void k_conv(const int* enc, const int* dec, const float* convb,
                       const float* T, float* xc) {
    int w = blockIdx.x;                            // grid 800, block 128
    int b = w / 400, n = w % 400;
    __shared__ int ids[16];
    int f = threadIdx.x;
    if (f < 16) {
        ids[f] = (n < 250) ? enc[(b * 250 + n) * 16 + f]
                           : dec[(b * 150 + (n - 250)) * 16 + f];
    }
    __syncthreads();
    float best = -1e30f;
    for (int p = 0; p < 16; ++p) {
        float s = 0.f;
#pragma unroll
        for (int k = 0; k < 5; ++k) {
            int q = p + k - 2;
            if (q >= 0 && q < 16) s += T[(k * 128 + ids[q]) * 128 + f];
        }
        best = fmaxf(best, s);
    }
    xc[w * 128 + f] = fmaxf(best + convb[f], 0.f);
}

// ---------- K2: x = xc @ hstW + hstb -> [800][256]
__global__ void k_hst(const float* xc, const float* W, const float* bias, float* x) {
    int w = blockIdx.x, t = threadIdx.x;           // grid 800, block 256
    __shared__ float xr[128];
    if (t < 128) xr[t] = xc[w * 128 + t];
    __syncthreads();
    float acc = bias[t];
    for (int c = 0; c < 128; ++c) acc += xr[c] * W[c * 256 + t];
    x[w * 256 + t] = acc;
}

// ---------- K3: Wh + fused f1/f2. 4 rows/block, attW staged via LDS chunks.
__global__ __launch_bounds__(256) void k_wh(const float* x, const float* attW,
                                            const float* a1g, const float* a2g,
                                            float* Wh, float* f1, float* f2) {
    int blk = blockIdx.x, t = threadIdx.x;         // grid 200, block 256
    int w0 = blk * 4;                              // 4 rows, never crosses b (400%4==0)
    __shared__ float Wl[64][256];
    __shared__ float xr[4][256];
#pragma unroll
    for (int rw = 0; rw < 4; ++rw) xr[rw][t] = x[(w0 + rw) * 256 + t];
    float acc[4] = {0.f, 0.f, 0.f, 0.f};
    int h = t >> 5, k = t & 31;
    for (int c = 0; c < 4; ++c) {
        __syncthreads();                           // Wl safe to overwrite
        for (int i = t; i < 16384; i += 256) {
            int dd = i >> 8, cc = i & 255;
            Wl[dd][cc] = attW[(cc >> 5) * 8192 + (c * 64 + dd) * 32 + (cc & 31)];
        }
        __syncthreads();
        for (int dd = 0; dd < 64; ++dd) {
            float wv = Wl[dd][t];
            int d = c * 64 + dd;
#pragma unroll
            for (int rw = 0; rw < 4; ++rw) acc[rw] += xr[rw][d] * wv;
        }
    }
    float a1v = a1g[t], a2v = a2g[t];
    int b = w0 / 400;
    int bh = b * 8 + h;
#pragma unroll
    for (int rw = 0; rw < 4; ++rw) {
        int n = (w0 + rw) % 400;
        Wh[(bh * 400 + n) * 32 + k] = acc[rw];
        float v1 = acc[rw] * a1v, v2 = acc[rw] * a2v;
#pragma unroll
        for (int mm = 16; mm >= 1; mm >>= 1) {
            v1 += __shfl_xor(v1, mm, 64);
            v2 += __shfl_xor(v2, mm, 64);
        }
        if (k == 0) { f1[bh * 400 + n] = v1; f2[bh * 400 + n] = v2; }
    }
}

// ---------- K4: softmax + PV + elu. 16 rows/block, 4 rows per barrier-iter.
#define WST 33
__global__ __launch_bounds__(256) void k_attn(const float* Wh, const float* f1g,
                                              const float* f2g, float* xout) {
    int tile = blockIdx.x, bh = blockIdx.y;        // grid (25, 16)
    int b = bh >> 3, h = bh & 7;
    int t = threadIdx.x;
    int n0 = tile * 16;
    __shared__ float Whl[400 * WST];
    __shared__ float f2l[400];
    __shared__ float pl[4][400];
    __shared__ float f1l[16];
    __shared__ float red[4][2][32];
    __shared__ float sred[2][4][4];
    __shared__ float wmax[4];

    const float* Whg = Wh + bh * 12800;
    for (int i = t; i < 12800; i += 256)
        Whl[(i >> 5) * WST + (i & 31)] = Whg[i];
    float fm = -1e30f;
    for (int m = t; m < 400; m += 256) {
        float v = f2g[bh * 400 + m];
        f2l[m] = v;
        fm = fmaxf(fm, v);
    }
    if (t < 16) f1l[t] = f1g[bh * 400 + n0 + t];
#pragma unroll
    for (int mm = 32; mm >= 1; mm >>= 1) fm = fmaxf(fm, __shfl_xor(fm, mm, 64));
    if ((t & 63) == 0) wmax[t >> 6] = fm;
    __syncthreads();
    float fmax2 = fmaxf(fmaxf(wmax[0], wmax[1]), fmaxf(wmax[2], wmax[3]));

    int kk = t & 31, g = t >> 5;                   // P2 roles: row g&3, m-parity g>>2
    for (int it = 0; it < 4; ++it) {
        // P1: p + denominator partials for 4 rows
        float ps[4];
#pragma unroll
        for (int rr = 0; rr < 4; ++rr) {
            float f1n = f1l[it * 4 + rr];
            float rowm = f1n + fmax2;              // leaky is monotone
            rowm = rowm > 0.f ? rowm : 0.2f * rowm;
            float p_s = 0.f;
            for (int m = t; m < 400; m += 256) {
                float e = f1n + f2l[m];
                e = e > 0.f ? e : 0.2f * e;
                float p = __expf(e - rowm);
                pl[rr][m] = p;
                p_s += p;
            }
            ps[rr] = p_s;
        }
#pragma unroll
        for (int rr = 0; rr < 4; ++rr) {
            float v = ps[rr];
#pragma unroll
            for (int mm = 32; mm >= 1; mm >>= 1) v += __shfl_xor(v, mm, 64);
            if ((t & 63) == 0) sred[it & 1][rr][t >> 6] = v;
        }
        __syncthreads();
        // P2: PV partials — thread (g,kk): row g&3, m ≡ (g>>2) (mod 2)
        {
            int rw = g & 3, gm = g >> 2;
            float a0 = 0.f;
            for (int m = gm; m < 400; m += 2)
                a0 += pl[rw][m] * Whl[m * WST + kk];
            red[rw][gm][kk] = a0;
        }
        __syncthreads();
        // P3: combine, normalize, elu, store (sred parity-buffered vs next P1)
        if (t < 128) {
            int rw3 = t >> 5, k3 = t & 31;
            float s = sred[it & 1][rw3][0] + sred[it & 1][rw3][1]
                    + sred[it & 1][rw3][2] + sred[it & 1][rw3][3];
            float o = (red[rw3][0][k3] + red[rw3][1][k3]) / s;
            o = o > 0.f ? o : (__expf(o) - 1.f);   // elu
            int n = n0 + it * 4 + rw3;
            xout[(b * 400 + n) * 256 + h * 32 + k3] = o;
        }
    }
}

// ---------- K5: out[r][v] = sum_d x[b,250+dn,d]*W[d][v] + b[v]
__global__ __launch_bounds__(256) void k_out(const float* x, const float* W,
                                             const float* bias, float* out) {
    int vt = blockIdx.x, rg = blockIdx.y, t = threadIdx.x;  // grid (20,30)
    __shared__ float xr[10][256];
    int r0 = rg * 10;                              // 150%10==0: never crosses b
    int b = r0 / 150, n0 = 250 + (r0 % 150);
    for (int i = t; i < 2560; i += 256) {
        int rr = i >> 8, dd = i & 255;
        xr[rr][dd] = x[(b * 400 + n0 + rr) * 256 + dd];
    }
    __syncthreads();
    if (t >= 250) return;
    int v = vt * 250 + t;
    float acc[10];
#pragma unroll
    for (int rr = 0; rr < 10; ++rr) acc[rr] = 0.f;
    for (int dd = 0; dd < 256; ++dd) {
        float wv = W[dd * 5000 + v];
#pragma unroll
        for (int rr = 0; rr < 10; ++rr) acc[rr] += xr[rr][dd] * wv;
    }
    float bv = bias[v];
#pragma unroll
    for (int rr = 0; rr < 10; ++rr)
        out[(r0 + rr) * 5000 + v] = acc[rr] + bv;
}

extern "C" void kernel_launch(void* const* d_in, const int* in_sizes, int n_in,
                              void* d_out, int out_size, void* d_ws, size_t ws_size,
                              hipStream_t stream) {
    const int*   enc   = (const int*)d_in[0];
    const int*   dec   = (const int*)d_in[1];
    const float* emb   = (const float*)d_in[3];
    const float* convw = (const float*)d_in[4];
    const float* convb = (const float*)d_in[5];
    const float* hstW  = (const float*)d_in[6];
    const float* hstb  = (const float*)d_in[7];
    const float* attW  = (const float*)d_in[15];
    const float* a1    = (const float*)d_in[16];
    const float* a2    = (const float*)d_in[17];
    const float* outW  = (const float*)d_in[18];
    const float* outb  = (const float*)d_in[19];
    float* out = (float*)d_out;

    char* ws = (char*)d_ws;
    float* T   = (float*)ws; ws += 5 * 128 * 128 * 4;
    float* xc  = (float*)ws; ws += 800 * 128 * 4;
    float* xA  = (float*)ws; ws += 800 * 256 * 4;
    float* xB  = (float*)ws; ws += 800 * 256 * 4;
    float* Wh  = (float*)ws; ws += 16 * 400 * 32 * 4;
    float* f1  = (float*)ws; ws += 16 * 400 * 4;
    float* f2  = (float*)ws; ws += 16 * 400 * 4;

    k_table<<<128, 128, 0, stream>>>(emb, convw, T);
    k_conv<<<800, 128, 0, stream>>>(enc, dec, convb, T, xc);
    k_hst<<<800, 256, 0, stream>>>(xc, hstW, hstb, xA);

    float* xin = xA;
    float* xo  = xB;
    for (int it = 0; it < 2; ++it) {
        k_wh<<<200, 256, 0, stream>>>(xin, attW, a1, a2, Wh, f1, f2);
        k_attn<<<dim3(25, 16), 256, 0, stream>>>(Wh, f1, f2, xo);
        float* tmp = xin; xin = xo; xo = tmp;
    }
    k_out<<<dim3(20, 30), 256, 0, stream>>>(xin, outW, outb, out);
}

// Round 6
// 163.508 us; speedup vs baseline: 1.5179x; 1.3403x over previous
//
#include <hip/hip_runtime.h>
#include <hip/hip_bf16.h>
#include <math.h>

// Shapes: B=2, Le=250, Ld=150, N=400, Wl=16, Vin=128, E=64, F=128, K=5
//         H=8, hid=32, d=256, Vout=5000
// Inputs fp32, output fp32 (verified round 4). fixed_graph/dg_* dead:
// adj=clip(sigmoid+fixed,0,1) strictly positive => unmasked softmax.
// Round-5 lesson: k_out was latency-bound (VGPR=32 => ~1-2 loads in flight;
// fp32 W=5.12MB > 4MiB L2/XCD => L3 latency ~600cy). Fix: bf16 W (L2-resident)
// + 2 cols/thread dword loads + unroll 8 for MLP.

__device__ __forceinline__ float bf2f_raw(unsigned int u) {
    union { unsigned int i; float f; } cv; cv.i = u << 16; return cv.f;
}

// ---------- K0: T[k5][v][f] = sum_e emb[v][e] * convw[f][e][k5]
__global__ void k_table(const float* emb, const float* convw, float* T) {
    int v = blockIdx.x, f = threadIdx.x;          // grid 128, block 128
    __shared__ float er[64];
    if (f < 64) er[f] = emb[v * 64 + f];
    __syncthreads();
    float acc[5] = {0.f, 0.f, 0.f, 0.f, 0.f};
    const float* w = convw + f * 320;             // convw[f][e][k5]
    for (int e = 0; e < 64; ++e) {
        float xe = er[e];
#pragma unroll
        for (int k = 0; k < 5; ++k) acc[k] += xe * w[e * 5 + k];
    }
#pragma unroll
    for (int k = 0; k < 5; ++k) T[(k * 128 + v) * 128 + f] = acc[k];
}

// ---------- K1: char conv via table + bias + relu + maxpool -> xc[800][128]
__global__ void k_conv(const int* enc, const int* dec, const float* convb,
                       const float* T, float* xc) {
    int w = blockIdx.x;                            // grid 800, block 128
    int b = w / 400, n = w % 400;
    __shared__ int ids[16];
    int f = threadIdx.x;
    if (f < 16) {
        ids[f] = (n < 250) ? enc[(b * 250 + n) * 16 + f]
                           : dec[(b * 150 + (n - 250)) * 16 + f];
    }
    __syncthreads();
    float best = -1e30f;
    for (int p = 0; p < 16; ++p) {
        float s = 0.f;
#pragma unroll
        for (int k = 0; k < 5; ++k) {
            int q = p + k - 2;
            if (q >= 0 && q < 16) s += T[(k * 128 + ids[q]) * 128 + f];
        }
        best = fmaxf(best, s);
    }
    xc[w * 128 + f] = fmaxf(best + convb[f], 0.f);
}

// ---------- K2: x = xc @ hstW + hstb -> [800][256]
__global__ void k_hst(const float* xc, const float* W, const float* bias, float* x) {
    int w = blockIdx.x, t = threadIdx.x;           // grid 800, block 256
    __shared__ float xr[128];
    if (t < 128) xr[t] = xc[w * 128 + t];
    __syncthreads();
    float acc = bias[t];
    for (int c = 0; c < 128; ++c) acc += xr[c] * W[c * 256 + t];
    x[w * 256 + t] = acc;
}

// ---------- K3: Wh + fused f1/f2. 2 rows/block, attW streamed from L2.
__global__ __launch_bounds__(256) void k_wh(const float* x, const float* attW,
                                            const float* a1g, const float* a2g,
                                            float* Wh, float* f1, float* f2) {
    int blk = blockIdx.x, t = threadIdx.x;         // grid 400, block 256
    int w0 = blk * 2;                              // 2 rows, never crosses b
    int h = t >> 5, k = t & 31;
    __shared__ float xr[2][256];
    for (int i = t; i < 512; i += 256) xr[i >> 8][i & 255] = x[w0 * 256 + i];
    __syncthreads();
    float acc0 = 0.f, acc1 = 0.f;
    const float* Wp = attW + h * 8192 + k;         // per-wave: 2x128B segments/load
#pragma unroll 8
    for (int d = 0; d < 256; ++d) {
        float wv = Wp[d * 32];
        acc0 += xr[0][d] * wv;
        acc1 += xr[1][d] * wv;
    }
    float a1v = a1g[t], a2v = a2g[t];
    int b = w0 / 400;
    int bh = b * 8 + h;
    float accs[2] = {acc0, acc1};
#pragma unroll
    for (int rw = 0; rw < 2; ++rw) {
        int n = (w0 + rw) % 400;
        Wh[(bh * 400 + n) * 32 + k] = accs[rw];
        float v1 = accs[rw] * a1v, v2 = accs[rw] * a2v;
#pragma unroll
        for (int mm = 16; mm >= 1; mm >>= 1) {
            v1 += __shfl_xor(v1, mm, 64);
            v2 += __shfl_xor(v2, mm, 64);
        }
        if (k == 0) { f1[bh * 400 + n] = v1; f2[bh * 400 + n] = v2; }
    }
}

// ---------- K4: softmax + PV + elu. 16 rows/block, 4 rows per barrier-iter.
#define WST 33
__global__ __launch_bounds__(256) void k_attn(const float* Wh, const float* f1g,
                                              const float* f2g, float* xout) {
    int tile = blockIdx.x, bh = blockIdx.y;        // grid (25, 16)
    int b = bh >> 3, h = bh & 7;
    int t = threadIdx.x;
    int n0 = tile * 16;
    __shared__ float Whl[400 * WST];
    __shared__ float f2l[400];
    __shared__ float pl[4][400];
    __shared__ float f1l[16];
    __shared__ float red[4][2][32];
    __shared__ float sred[2][4][4];
    __shared__ float wmax[4];

    const float* Whg = Wh + bh * 12800;
    for (int i = t; i < 12800; i += 256)
        Whl[(i >> 5) * WST + (i & 31)] = Whg[i];
    float fm = -1e30f;
    for (int m = t; m < 400; m += 256) {
        float v = f2g[bh * 400 + m];
        f2l[m] = v;
        fm = fmaxf(fm, v);
    }
    if (t < 16) f1l[t] = f1g[bh * 400 + n0 + t];
#pragma unroll
    for (int mm = 32; mm >= 1; mm >>= 1) fm = fmaxf(fm, __shfl_xor(fm, mm, 64));
    if ((t & 63) == 0) wmax[t >> 6] = fm;
    __syncthreads();
    float fmax2 = fmaxf(fmaxf(wmax[0], wmax[1]), fmaxf(wmax[2], wmax[3]));

    int kk = t & 31, g = t >> 5;
    for (int it = 0; it < 4; ++it) {
        float ps[4];
#pragma unroll
        for (int rr = 0; rr < 4; ++rr) {
            float f1n = f1l[it * 4 + rr];
            float rowm = f1n + fmax2;              // leaky is monotone
            rowm = rowm > 0.f ? rowm : 0.2f * rowm;
            float p_s = 0.f;
            for (int m = t; m < 400; m += 256) {
                float e = f1n + f2l[m];
                e = e > 0.f ? e : 0.2f * e;
                float p = __expf(e - rowm);
                pl[rr][m] = p;
                p_s += p;
            }
            ps[rr] = p_s;
        }
#pragma unroll
        for (int rr = 0; rr < 4; ++rr) {
            float v = ps[rr];
#pragma unroll
            for (int mm = 32; mm >= 1; mm >>= 1) v += __shfl_xor(v, mm, 64);
            if ((t & 63) == 0) sred[it & 1][rr][t >> 6] = v;
        }
        __syncthreads();
        {
            int rw = g & 3, gm = g >> 2;
            float a0 = 0.f;
            for (int m = gm; m < 400; m += 2)
                a0 += pl[rw][m] * Whl[m * WST + kk];
            red[rw][gm][kk] = a0;
        }
        __syncthreads();
        if (t < 128) {
            int rw3 = t >> 5, k3 = t & 31;
            float s = sred[it & 1][rw3][0] + sred[it & 1][rw3][1]
                    + sred[it & 1][rw3][2] + sred[it & 1][rw3][3];
            float o = (red[rw3][0][k3] + red[rw3][1][k3]) / s;
            o = o > 0.f ? o : (__expf(o) - 1.f);   // elu
            int n = n0 + it * 4 + rw3;
            xout[(b * 400 + n) * 256 + h * 32 + k3] = o;
        }
    }
}

// ---------- K5a: out_W fp32 -> bf16 (2.56 MB, L2-resident afterwards)
__global__ void k_w2b(const float* W, unsigned short* Wb, int n) {
    int i = blockIdx.x * 256 + threadIdx.x;
    if (i < n) {
        __hip_bfloat16 h = __float2bfloat16(W[i]);
        Wb[i] = *reinterpret_cast<unsigned short*>(&h);
    }
}

// ---------- K5: out[r][v] = sum_d x[b,250+dn,d]*Wb[d][v] + b[v]
__global__ __launch_bounds__(256) void k_out(const float* x, const unsigned short* Wb,
                                             const float* bias, float* out) {
    int vt = blockIdx.x, rg = blockIdx.y, t = threadIdx.x;  // grid (10,50)
    __shared__ float xr[6][256];
    int r0 = rg * 6;                               // 150%6==0: never crosses b
    int b = r0 / 150, n0 = 250 + (r0 % 150);
    for (int i = t; i < 1536; i += 256) {
        int rr = i >> 8, dd = i & 255;
        xr[rr][dd] = x[(b * 400 + n0 + rr) * 256 + dd];
    }
    __syncthreads();
    int v = vt * 512 + t * 2;                      // 2 cols/thread, dword load
    if (v >= 5000) return;
    float acc[6][2];
#pragma unroll
    for (int rr = 0; rr < 6; ++rr) { acc[rr][0] = 0.f; acc[rr][1] = 0.f; }
    const unsigned short* Wp = Wb + v;
#pragma unroll 8
    for (int dd = 0; dd < 256; ++dd) {
        unsigned int wu = *reinterpret_cast<const unsigned int*>(Wp + dd * 5000);
        float w0 = bf2f_raw(wu & 0xFFFFu);
        float w1 = bf2f_raw(wu >> 16);
#pragma unroll
        for (int rr = 0; rr < 6; ++rr) {
            float xv = xr[rr][dd];
            acc[rr][0] += xv * w0;
            acc[rr][1] += xv * w1;
        }
    }
    float b0 = bias[v], b1 = bias[v + 1];
#pragma unroll
    for (int rr = 0; rr < 6; ++rr) {
        out[(r0 + rr) * 5000 + v]     = acc[rr][0] + b0;
        out[(r0 + rr) * 5000 + v + 1] = acc[rr][1] + b1;
    }
}

extern "C" void kernel_launch(void* const* d_in, const int* in_sizes, int n_in,
                              void* d_out, int out_size, void* d_ws, size_t ws_size,
                              hipStream_t stream) {
    const int*   enc   = (const int*)d_in[0];
    const int*   dec   = (const int*)d_in[1];
    const float* emb   = (const float*)d_in[3];
    const float* convw = (const float*)d_in[4];
    const float* convb = (const float*)d_in[5];
    const float* hstW  = (const float*)d_in[6];
    const float* hstb  = (const float*)d_in[7];
    const float* attW  = (const float*)d_in[15];
    const float* a1    = (const float*)d_in[16];
    const float* a2    = (const float*)d_in[17];
    const float* outW  = (const float*)d_in[18];
    const float* outb  = (const float*)d_in[19];
    float* out = (float*)d_out;

    char* ws = (char*)d_ws;
    float* T   = (float*)ws; ws += 5 * 128 * 128 * 4;
    float* xc  = (float*)ws; ws += 800 * 128 * 4;
    float* xA  = (float*)ws; ws += 800 * 256 * 4;
    float* xB  = (float*)ws; ws += 800 * 256 * 4;
    float* Wh  = (float*)ws; ws += 16 * 400 * 32 * 4;
    float* f1  = (float*)ws; ws += 16 * 400 * 4;
    float* f2  = (float*)ws; ws += 16 * 400 * 4;
    unsigned short* Wb = (unsigned short*)ws; ws += 256 * 5000 * 2;

    k_w2b<<<5000, 256, 0, stream>>>(outW, Wb, 256 * 5000);
    k_table<<<128, 128, 0, stream>>>(emb, convw, T);
    k_conv<<<800, 128, 0, stream>>>(enc, dec, convb, T, xc);
    k_hst<<<800, 256, 0, stream>>>(xc, hstW, hstb, xA);

    float* xin = xA;
    float* xo  = xB;
    for (int it = 0; it < 2; ++it) {
        k_wh<<<400, 256, 0, stream>>>(xin, attW, a1, a2, Wh, f1, f2);
        k_attn<<<dim3(25, 16), 256, 0, stream>>>(Wh, f1, f2, xo);
        float* tmp = xin; xin = xo; xo = tmp;
    }
    k_out<<<dim3(10, 50), 256, 0, stream>>>(xin, Wb, outb, out);
}

// Round 7
// 115.167 us; speedup vs baseline: 2.1551x; 1.4197x over previous
//
#include <hip/hip_runtime.h>
#include <hip/hip_bf16.h>
#include <math.h>

// Shapes: B=2, Le=250, Ld=150, N=400, Wl=16, Vin=128, E=64, F=128, K=5
//         H=8, hid=32, d=256, Vout=5000
// Inputs fp32, output fp32 (verified round 4). fixed_graph/dg_* dead:
// adj=clip(sigmoid+fixed,0,1) strictly positive => unmasked softmax.
// Round-6 lesson: k_attn was LDS-instruction-bound (6400 ds_read_b32/block in
// PV). Fix: WST=36 + ds_read_b128 4-col x 4-row PV (1 b128 amortized over 4
// rows), DPP-only shuffles (xor 1/2/4; xor>=8 lowers to ds_swizzle = LDS pipe).

__device__ __forceinline__ float bf2f_raw(unsigned int u) {
    union { unsigned int i; float f; } cv; cv.i = u << 16; return cv.f;
}

// ---------- K0: T[k5][v][f] = sum_e emb[v][e] * convw[f][e][k5]
__global__ void k_table(const float* emb, const float* convw, float* T) {
    int v = blockIdx.x, f = threadIdx.x;          // grid 128, block 128
    __shared__ float er[64];
    if (f < 64) er[f] = emb[v * 64 + f];
    __syncthreads();
    float acc[5] = {0.f, 0.f, 0.f, 0.f, 0.f};
    const float* w = convw + f * 320;             // convw[f][e][k5]
    for (int e = 0; e < 64; ++e) {
        float xe = er[e];
#pragma unroll
        for (int k = 0; k < 5; ++k) acc[k] += xe * w[e * 5 + k];
    }
#pragma unroll
    for (int k = 0; k < 5; ++k) T[(k * 128 + v) * 128 + f] = acc[k];
}

// ---------- K1: char conv via table + bias + relu + maxpool -> xc[800][128]
__global__ void k_conv(const int* enc, const int* dec, const float* convb,
                       const float* T, float* xc) {
    int w = blockIdx.x;                            // grid 800, block 128
    int b = w / 400, n = w % 400;
    __shared__ int ids[16];
    int f = threadIdx.x;
    if (f < 16) {
        ids[f] = (n < 250) ? enc[(b * 250 + n) * 16 + f]
                           : dec[(b * 150 + (n - 250)) * 16 + f];
    }
    __syncthreads();
    float best = -1e30f;
    for (int p = 0; p < 16; ++p) {
        float s = 0.f;
#pragma unroll
        for (int k = 0; k < 5; ++k) {
            int q = p + k - 2;
            if (q >= 0 && q < 16) s += T[(k * 128 + ids[q]) * 128 + f];
        }
        best = fmaxf(best, s);
    }
    xc[w * 128 + f] = fmaxf(best + convb[f], 0.f);
}

// ---------- K2: x = xc @ hstW + hstb -> [800][256]
__global__ void k_hst(const float* xc, const float* W, const float* bias, float* x) {
    int w = blockIdx.x, t = threadIdx.x;           // grid 800, block 256
    __shared__ float xr[128];
    if (t < 128) xr[t] = xc[w * 128 + t];
    __syncthreads();
    float acc = bias[t];
    for (int c = 0; c < 128; ++c) acc += xr[c] * W[c * 256 + t];
    x[w * 256 + t] = acc;
}

// ---------- K3: Wh + fused f1/f2. 2 rows/block, attW streamed from L2.
__global__ __launch_bounds__(256) void k_wh(const float* x, const float* attW,
                                            const float* a1g, const float* a2g,
                                            float* Wh, float* f1, float* f2) {
    int blk = blockIdx.x, t = threadIdx.x;         // grid 400, block 256
    int w0 = blk * 2;                              // 2 rows, never crosses b
    int h = t >> 5, k = t & 31;
    __shared__ float xr[2][256];
    for (int i = t; i < 512; i += 256) xr[i >> 8][i & 255] = x[w0 * 256 + i];
    __syncthreads();
    float acc0 = 0.f, acc1 = 0.f;
    const float* Wp = attW + h * 8192 + k;         // per-wave: 2x128B segments/load
#pragma unroll 8
    for (int d = 0; d < 256; ++d) {
        float wv = Wp[d * 32];
        acc0 += xr[0][d] * wv;
        acc1 += xr[1][d] * wv;
    }
    float a1v = a1g[t], a2v = a2g[t];
    int b = w0 / 400;
    int bh = b * 8 + h;
    float accs[2] = {acc0, acc1};
#pragma unroll
    for (int rw = 0; rw < 2; ++rw) {
        int n = (w0 + rw) % 400;
        Wh[(bh * 400 + n) * 32 + k] = accs[rw];
        float v1 = accs[rw] * a1v, v2 = accs[rw] * a2v;
#pragma unroll
        for (int mm = 16; mm >= 1; mm >>= 1) {
            v1 += __shfl_xor(v1, mm, 64);
            v2 += __shfl_xor(v2, mm, 64);
        }
        if (k == 0) { f1[bh * 400 + n] = v1; f2[bh * 400 + n] = v2; }
    }
}

// ---------- K4: softmax + PV + elu. 16 rows/block, 4 rows per barrier-iter.
// PV via ds_read_b128: thread (g=t&7, kq=(t>>3)&7, wave w): cols kq*4..+3,
// m = (g + 8w) + 32j. Bank-start 4(g+kq) mod 32 -> 8 disjoint groups: no
// conflict beyond the mandatory 8 phases. g-reduction via DPP xor 1/2/4.
#define WST 36
__global__ __launch_bounds__(256) void k_attn(const float* Wh, const float* f1g,
                                              const float* f2g, float* xout) {
    int tile = blockIdx.x, bh = blockIdx.y;        // grid (25, 16)
    int b = bh >> 3, h = bh & 7;
    int t = threadIdx.x;
    int n0 = tile * 16;
    __shared__ float Whl[400 * WST];               // 57.6 KB, rows 16B-aligned
    __shared__ float f2l[400];
    __shared__ float pl[4][400];
    __shared__ float f1l[16];
    __shared__ float red[4][8][4][4];              // [wave][kq][rw][c]
    __shared__ float sred[2][4][4];
    __shared__ float wmax[4];

    const float4* Whg4 = (const float4*)(Wh + bh * 12800);
    for (int i = t; i < 3200; i += 256) {
        float4 v = Whg4[i];
        int m = i >> 3, k4 = i & 7;
        *(float4*)&Whl[m * WST + k4 * 4] = v;
    }
    float fm = -1e30f;
    for (int m = t; m < 400; m += 256) {
        float v = f2g[bh * 400 + m];
        f2l[m] = v;
        fm = fmaxf(fm, v);
    }
    if (t < 16) f1l[t] = f1g[bh * 400 + n0 + t];
#pragma unroll
    for (int mm = 32; mm >= 1; mm >>= 1) fm = fmaxf(fm, __shfl_xor(fm, mm, 64));
    if ((t & 63) == 0) wmax[t >> 6] = fm;
    __syncthreads();
    float fmax2 = fmaxf(fmaxf(wmax[0], wmax[1]), fmaxf(wmax[2], wmax[3]));

    int g = t & 7, kq = (t >> 3) & 7, wv = t >> 6;
    int gm = g + 8 * wv;                           // m-group 0..31
    for (int it = 0; it < 4; ++it) {
        // P1: p + denominator partials for 4 rows
        float ps[4];
#pragma unroll
        for (int rr = 0; rr < 4; ++rr) {
            float f1n = f1l[it * 4 + rr];
            float rowm = f1n + fmax2;              // leaky is monotone
            rowm = rowm > 0.f ? rowm : 0.2f * rowm;
            float p_s = 0.f;
            for (int m = t; m < 400; m += 256) {
                float e = f1n + f2l[m];
                e = e > 0.f ? e : 0.2f * e;
                float p = __expf(e - rowm);
                pl[rr][m] = p;
                p_s += p;
            }
            ps[rr] = p_s;
        }
#pragma unroll
        for (int rr = 0; rr < 4; ++rr) {
            float v = ps[rr];
#pragma unroll
            for (int mm = 32; mm >= 1; mm >>= 1) v += __shfl_xor(v, mm, 64);
            if ((t & 63) == 0) sred[it & 1][rr][t >> 6] = v;
        }
        __syncthreads();
        // P2: 4 rows x 4 cols per thread; 1 b128 Wh read amortized over rows
        float a[4][4];
#pragma unroll
        for (int rr = 0; rr < 4; ++rr)
#pragma unroll
            for (int c = 0; c < 4; ++c) a[rr][c] = 0.f;
        for (int m = gm; m < 400; m += 32) {
            float4 w4 = *(const float4*)&Whl[m * WST + kq * 4];
            float p0 = pl[0][m], p1 = pl[1][m], p2 = pl[2][m], p3 = pl[3][m];
            a[0][0] += p0 * w4.x; a[0][1] += p0 * w4.y; a[0][2] += p0 * w4.z; a[0][3] += p0 * w4.w;
            a[1][0] += p1 * w4.x; a[1][1] += p1 * w4.y; a[1][2] += p1 * w4.z; a[1][3] += p1 * w4.w;
            a[2][0] += p2 * w4.x; a[2][1] += p2 * w4.y; a[2][2] += p2 * w4.z; a[2][3] += p2 * w4.w;
            a[3][0] += p3 * w4.x; a[3][1] += p3 * w4.y; a[3][2] += p3 * w4.z; a[3][3] += p3 * w4.w;
        }
        // reduce over g (lane bits 0..2 -> DPP shuffles, stays off the LDS pipe)
#pragma unroll
        for (int rr = 0; rr < 4; ++rr)
#pragma unroll
            for (int c = 0; c < 4; ++c) {
                float v = a[rr][c];
                v += __shfl_xor(v, 1, 64);
                v += __shfl_xor(v, 2, 64);
                v += __shfl_xor(v, 4, 64);
                a[rr][c] = v;
            }
        if (g == 0) {
#pragma unroll
            for (int rr = 0; rr < 4; ++rr)
#pragma unroll
                for (int c = 0; c < 4; ++c) red[wv][kq][rr][c] = a[rr][c];
        }
        __syncthreads();
        // P3: combine 4 wave-partials, normalize, elu, store
        if (t < 128) {
            int rw3 = t >> 5, kk = t & 31;
            int q3 = kk >> 2, c3 = kk & 3;
            float s = sred[it & 1][rw3][0] + sred[it & 1][rw3][1]
                    + sred[it & 1][rw3][2] + sred[it & 1][rw3][3];
            float o = (red[0][q3][rw3][c3] + red[1][q3][rw3][c3]
                     + red[2][q3][rw3][c3] + red[3][q3][rw3][c3]) / s;
            o = o > 0.f ? o : (__expf(o) - 1.f);   // elu
            int n = n0 + it * 4 + rw3;
            xout[(b * 400 + n) * 256 + h * 32 + kk] = o;
        }
    }
}

// ---------- K5a: out_W fp32 -> bf16 (2.56 MB, L2-resident afterwards)
__global__ void k_w2b(const float* W, unsigned short* Wb, int n) {
    int i = blockIdx.x * 256 + threadIdx.x;
    if (i < n) {
        __hip_bfloat16 h = __float2bfloat16(W[i]);
        Wb[i] = *reinterpret_cast<unsigned short*>(&h);
    }
}

// ---------- K5: out[r][v] = sum_d x[b,250+dn,d]*Wb[d][v] + b[v]
__global__ __launch_bounds__(256) void k_out(const float* x, const unsigned short* Wb,
                                             const float* bias, float* out) {
    int vt = blockIdx.x, rg = blockIdx.y, t = threadIdx.x;  // grid (10,50)
    __shared__ float xr[6][256];
    int r0 = rg * 6;                               // 150%6==0: never crosses b
    int b = r0 / 150, n0 = 250 + (r0 % 150);
    for (int i = t; i < 1536; i += 256) {
        int rr = i >> 8, dd = i & 255;
        xr[rr][dd] = x[(b * 400 + n0 + rr) * 256 + dd];
    }
    __syncthreads();
    int v = vt * 512 + t * 2;                      // 2 cols/thread, dword load
    if (v >= 5000) return;
    float acc[6][2];
#pragma unroll
    for (int rr = 0; rr < 6; ++rr) { acc[rr][0] = 0.f; acc[rr][1] = 0.f; }
    const unsigned short* Wp = Wb + v;
#pragma unroll 8
    for (int dd = 0; dd < 256; ++dd) {
        unsigned int wu = *reinterpret_cast<const unsigned int*>(Wp + dd * 5000);
        float w0 = bf2f_raw(wu & 0xFFFFu);
        float w1 = bf2f_raw(wu >> 16);
#pragma unroll
        for (int rr = 0; rr < 6; ++rr) {
            float xv = xr[rr][dd];
            acc[rr][0] += xv * w0;
            acc[rr][1] += xv * w1;
        }
    }
    float b0 = bias[v], b1 = bias[v + 1];
#pragma unroll
    for (int rr = 0; rr < 6; ++rr) {
        out[(r0 + rr) * 5000 + v]     = acc[rr][0] + b0;
        out[(r0 + rr) * 5000 + v + 1] = acc[rr][1] + b1;
    }
}

extern "C" void kernel_launch(void* const* d_in, const int* in_sizes, int n_in,
                              void* d_out, int out_size, void* d_ws, size_t ws_size,
                              hipStream_t stream) {
    const int*   enc   = (const int*)d_in[0];
    const int*   dec   = (const int*)d_in[1];
    const float* emb   = (const float*)d_in[3];
    const float* convw = (const float*)d_in[4];
    const float* convb = (const float*)d_in[5];
    const float* hstW  = (const float*)d_in[6];
    const float* hstb  = (const float*)d_in[7];
    const float* attW  = (const float*)d_in[15];
    const float* a1    = (const float*)d_in[16];
    const float* a2    = (const float*)d_in[17];
    const float* outW  = (const float*)d_in[18];
    const float* outb  = (const float*)d_in[19];
    float* out = (float*)d_out;

    char* ws = (char*)d_ws;
    float* T   = (float*)ws; ws += 5 * 128 * 128 * 4;
    float* xc  = (float*)ws; ws += 800 * 128 * 4;
    float* xA  = (float*)ws; ws += 800 * 256 * 4;
    float* xB  = (float*)ws; ws += 800 * 256 * 4;
    float* Wh  = (float*)ws; ws += 16 * 400 * 32 * 4;
    float* f1  = (float*)ws; ws += 16 * 400 * 4;
    float* f2  = (float*)ws; ws += 16 * 400 * 4;
    unsigned short* Wb = (unsigned short*)ws; ws += 256 * 5000 * 2;

    k_w2b<<<5000, 256, 0, stream>>>(outW, Wb, 256 * 5000);
    k_table<<<128, 128, 0, stream>>>(emb, convw, T);
    k_conv<<<800, 128, 0, stream>>>(enc, dec, convb, T, xc);
    k_hst<<<800, 256, 0, stream>>>(xc, hstW, hstb, xA);

    float* xin = xA;
    float* xo  = xB;
    for (int it = 0; it < 2; ++it) {
        k_wh<<<400, 256, 0, stream>>>(xin, attW, a1, a2, Wh, f1, f2);
        k_attn<<<dim3(25, 16), 256, 0, stream>>>(Wh, f1, f2, xo);
        float* tmp = xin; xin = xo; xo = tmp;
    }
    k_out<<<dim3(10, 50), 256, 0, stream>>>(xin, Wb, outb, out);
}

// Round 8
// 103.501 us; speedup vs baseline: 2.3980x; 1.1127x over previous
//
#include <hip/hip_runtime.h>
#include <hip/hip_bf16.h>
#include <math.h>

// Shapes: B=2, Le=250, Ld=150, N=400, Wl=16, Vin=128, E=64, F=128, K=5
//         H=8, hid=32, d=256, Vout=5000
// Inputs fp32, output fp32 (verified round 4). fixed_graph/dg_* dead:
// adj=clip(sigmoid+fixed,0,1) strictly positive => unmasked softmax.
// Round-7 lesson: k_attn still LDS-instruction-bound: P2 read p via 4 scalar
// b32 per m. Fix: p transposed to plT[m][4] -> P1 writes 1 b128/m, P2 reads
// 1 b128/m (8 consecutive 16B slots/wave = dense, conflict-free).
// Also fused: k_w2b+k_table -> k_prep; k_conv+k_hst -> k_convhst (xc stays
// in LDS; global xc buffer removed). 9 -> 7 dispatches.

__device__ __forceinline__ float bf2f_raw(unsigned int u) {
    union { unsigned int i; float f; } cv; cv.i = u << 16; return cv.f;
}
__device__ __forceinline__ unsigned short f2bf(float f) {
    __hip_bfloat16 h = __float2bfloat16(f);
    return *reinterpret_cast<unsigned short*>(&h);
}

// ---------- K0: fused { T[k5][v][f] = sum_e emb[v][e]*convw[f][e][k5] }
//                      { Wb = bf16(out_W) }
__global__ __launch_bounds__(256) void k_prep(const float* emb, const float* convw,
                                              float* T, const float* W,
                                              unsigned short* Wb) {
    int bid = blockIdx.x, t = threadIdx.x;
    if (bid < 128) {                               // table part: v = bid
        int v = bid;
        __shared__ float er[64];
        if (t < 64) er[t] = emb[v * 64 + t];
        __syncthreads();
        if (t < 128) {
            float acc[5] = {0.f, 0.f, 0.f, 0.f, 0.f};
            const float* w = convw + t * 320;      // convw[f][e][k5]
            for (int e = 0; e < 64; ++e) {
                float xe = er[e];
#pragma unroll
                for (int k = 0; k < 5; ++k) acc[k] += xe * w[e * 5 + k];
            }
#pragma unroll
            for (int k = 0; k < 5; ++k) T[(k * 128 + v) * 128 + t] = acc[k];
        }
    } else {                                       // w2b part: 512 elems/block
        int i0 = (bid - 128) * 512 + t * 2;        // 2500 blocks * 512 = 1.28M
        if (i0 < 256 * 5000) {
            float2 w2 = *reinterpret_cast<const float2*>(W + i0);
            unsigned int u = ((unsigned int)f2bf(w2.y) << 16) | f2bf(w2.x);
            *reinterpret_cast<unsigned int*>(Wb + i0) = u;
        }
    }
}

// ---------- K1: fused char-conv (+bias,relu,maxpool) and hst projection
__global__ __launch_bounds__(256) void k_convhst(const int* enc, const int* dec,
                                                 const float* convb, const float* T,
                                                 const float* hstW, const float* hstb,
                                                 float* x) {
    int w = blockIdx.x, t = threadIdx.x;           // grid 800, block 256
    int b = w / 400, n = w % 400;
    __shared__ int ids[16];
    __shared__ float xcl[128];
    if (t < 16) {
        ids[t] = (n < 250) ? enc[(b * 250 + n) * 16 + t]
                           : dec[(b * 150 + (n - 250)) * 16 + t];
    }
    __syncthreads();
    if (t < 128) {
        float best = -1e30f;
        for (int p = 0; p < 16; ++p) {
            float s = 0.f;
#pragma unroll
            for (int k = 0; k < 5; ++k) {
                int q = p + k - 2;
                if (q >= 0 && q < 16) s += T[(k * 128 + ids[q]) * 128 + t];
            }
            best = fmaxf(best, s);
        }
        xcl[t] = fmaxf(best + convb[t], 0.f);
    }
    __syncthreads();
    float acc = hstb[t];
    for (int c = 0; c < 128; ++c) acc += xcl[c] * hstW[c * 256 + t];
    x[w * 256 + t] = acc;
}

// ---------- K3: Wh + fused f1/f2. 2 rows/block, attW streamed from L2.
__global__ __launch_bounds__(256) void k_wh(const float* x, const float* attW,
                                            const float* a1g, const float* a2g,
                                            float* Wh, float* f1, float* f2) {
    int blk = blockIdx.x, t = threadIdx.x;         // grid 400, block 256
    int w0 = blk * 2;                              // 2 rows, never crosses b
    int h = t >> 5, k = t & 31;
    __shared__ float xr[2][256];
    for (int i = t; i < 512; i += 256) xr[i >> 8][i & 255] = x[w0 * 256 + i];
    __syncthreads();
    float acc0 = 0.f, acc1 = 0.f;
    const float* Wp = attW + h * 8192 + k;         // per-wave: 2x128B segments/load
#pragma unroll 8
    for (int d = 0; d < 256; ++d) {
        float wv = Wp[d * 32];
        acc0 += xr[0][d] * wv;
        acc1 += xr[1][d] * wv;
    }
    float a1v = a1g[t], a2v = a2g[t];
    int b = w0 / 400;
    int bh = b * 8 + h;
    float accs[2] = {acc0, acc1};
#pragma unroll
    for (int rw = 0; rw < 2; ++rw) {
        int n = (w0 + rw) % 400;
        Wh[(bh * 400 + n) * 32 + k] = accs[rw];
        float v1 = accs[rw] * a1v, v2 = accs[rw] * a2v;
#pragma unroll
        for (int mm = 16; mm >= 1; mm >>= 1) {
            v1 += __shfl_xor(v1, mm, 64);
            v2 += __shfl_xor(v2, mm, 64);
        }
        if (k == 0) { f1[bh * 400 + n] = v1; f2[bh * 400 + n] = v2; }
    }
}

// ---------- K4: softmax + PV + elu. 16 rows/block, 4 rows per barrier-iter.
// P1: thread t computes p for 4 rows at its m's -> ONE b128 store plT[m][4].
// P2: thread (g,kq,wave): m=g+8w+32j; 1 b128 Wh + 1 b128 plT per m
// (8 consecutive 16B slots/wave = dense, conflict-free). DPP xor 1/2/4 reduce.
#define WST 36
__global__ __launch_bounds__(256) void k_attn(const float* Wh, const float* f1g,
                                              const float* f2g, float* xout) {
    int tile = blockIdx.x, bh = blockIdx.y;        // grid (25, 16)
    int b = bh >> 3, h = bh & 7;
    int t = threadIdx.x;
    int n0 = tile * 16;
    __shared__ float Whl[400 * WST];               // 57.6 KB, rows 16B-aligned
    __shared__ float f2l[400];
    __shared__ float4 plT[400];                    // p transposed: [m][4 rows]
    __shared__ float f1l[16];
    __shared__ float red[4][8][4][4];              // [wave][kq][rw][c]
    __shared__ float sred[2][4][4];
    __shared__ float wmax[4];

    const float4* Whg4 = (const float4*)(Wh + bh * 12800);
    for (int i = t; i < 3200; i += 256) {
        float4 v = Whg4[i];
        int m = i >> 3, k4 = i & 7;
        *(float4*)&Whl[m * WST + k4 * 4] = v;
    }
    float fm = -1e30f;
    for (int m = t; m < 400; m += 256) {
        float v = f2g[bh * 400 + m];
        f2l[m] = v;
        fm = fmaxf(fm, v);
    }
    if (t < 16) f1l[t] = f1g[bh * 400 + n0 + t];
#pragma unroll
    for (int mm = 32; mm >= 1; mm >>= 1) fm = fmaxf(fm, __shfl_xor(fm, mm, 64));
    if ((t & 63) == 0) wmax[t >> 6] = fm;
    __syncthreads();
    float fmax2 = fmaxf(fmaxf(wmax[0], wmax[1]), fmaxf(wmax[2], wmax[3]));

    int g = t & 7, kq = (t >> 3) & 7, wv = t >> 6;
    int gm = g + 8 * wv;                           // m-group 0..31
    for (int it = 0; it < 4; ++it) {
        // P1: all 4 rows' p at this thread's m -> plT[m]; denominator partials
        float f1a = f1l[it * 4 + 0], f1b = f1l[it * 4 + 1];
        float f1c = f1l[it * 4 + 2], f1d = f1l[it * 4 + 3];
        float rm0 = f1a + fmax2; rm0 = rm0 > 0.f ? rm0 : 0.2f * rm0;
        float rm1 = f1b + fmax2; rm1 = rm1 > 0.f ? rm1 : 0.2f * rm1;
        float rm2 = f1c + fmax2; rm2 = rm2 > 0.f ? rm2 : 0.2f * rm2;
        float rm3 = f1d + fmax2; rm3 = rm3 > 0.f ? rm3 : 0.2f * rm3;
        float ps0 = 0.f, ps1 = 0.f, ps2 = 0.f, ps3 = 0.f;
        for (int m = t; m < 400; m += 256) {
            float f2v = f2l[m];
            float e0 = f1a + f2v; e0 = e0 > 0.f ? e0 : 0.2f * e0;
            float e1 = f1b + f2v; e1 = e1 > 0.f ? e1 : 0.2f * e1;
            float e2 = f1c + f2v; e2 = e2 > 0.f ? e2 : 0.2f * e2;
            float e3 = f1d + f2v; e3 = e3 > 0.f ? e3 : 0.2f * e3;
            float4 pv;
            pv.x = __expf(e0 - rm0); ps0 += pv.x;
            pv.y = __expf(e1 - rm1); ps1 += pv.y;
            pv.z = __expf(e2 - rm2); ps2 += pv.z;
            pv.w = __expf(e3 - rm3); ps3 += pv.w;
            plT[m] = pv;
        }
        {
            float v0 = ps0, v1 = ps1, v2 = ps2, v3 = ps3;
#pragma unroll
            for (int mm = 32; mm >= 1; mm >>= 1) {
                v0 += __shfl_xor(v0, mm, 64);
                v1 += __shfl_xor(v1, mm, 64);
                v2 += __shfl_xor(v2, mm, 64);
                v3 += __shfl_xor(v3, mm, 64);
            }
            if ((t & 63) == 0) {
                int wq = t >> 6;
                sred[it & 1][0][wq] = v0; sred[it & 1][1][wq] = v1;
                sred[it & 1][2][wq] = v2; sred[it & 1][3][wq] = v3;
            }
        }
        __syncthreads();
        // P2: 4 rows x 4 cols per thread; 1 b128 Wh + 1 b128 plT per m
        float a[4][4];
#pragma unroll
        for (int rr = 0; rr < 4; ++rr)
#pragma unroll
            for (int c = 0; c < 4; ++c) a[rr][c] = 0.f;
        for (int m = gm; m < 400; m += 32) {
            float4 w4 = *(const float4*)&Whl[m * WST + kq * 4];
            float4 p4 = plT[m];
            a[0][0] += p4.x * w4.x; a[0][1] += p4.x * w4.y; a[0][2] += p4.x * w4.z; a[0][3] += p4.x * w4.w;
            a[1][0] += p4.y * w4.x; a[1][1] += p4.y * w4.y; a[1][2] += p4.y * w4.z; a[1][3] += p4.y * w4.w;
            a[2][0] += p4.z * w4.x; a[2][1] += p4.z * w4.y; a[2][2] += p4.z * w4.z; a[2][3] += p4.z * w4.w;
            a[3][0] += p4.w * w4.x; a[3][1] += p4.w * w4.y; a[3][2] += p4.w * w4.z; a[3][3] += p4.w * w4.w;
        }
        // reduce over g (lane bits 0..2 -> DPP, stays off the LDS pipe)
#pragma unroll
        for (int rr = 0; rr < 4; ++rr)
#pragma unroll
            for (int c = 0; c < 4; ++c) {
                float v = a[rr][c];
                v += __shfl_xor(v, 1, 64);
                v += __shfl_xor(v, 2, 64);
                v += __shfl_xor(v, 4, 64);
                a[rr][c] = v;
            }
        if (g == 0) {
#pragma unroll
            for (int rr = 0; rr < 4; ++rr)
#pragma unroll
                for (int c = 0; c < 4; ++c) red[wv][kq][rr][c] = a[rr][c];
        }
        __syncthreads();
        // P3: combine 4 wave-partials, normalize, elu, store
        if (t < 128) {
            int rw3 = t >> 5, kk = t & 31;
            int q3 = kk >> 2, c3 = kk & 3;
            float s = sred[it & 1][rw3][0] + sred[it & 1][rw3][1]
                    + sred[it & 1][rw3][2] + sred[it & 1][rw3][3];
            float o = (red[0][q3][rw3][c3] + red[1][q3][rw3][c3]
                     + red[2][q3][rw3][c3] + red[3][q3][rw3][c3]) / s;
            o = o > 0.f ? o : (__expf(o) - 1.f);   // elu
            int n = n0 + it * 4 + rw3;
            xout[(b * 400 + n) * 256 + h * 32 + kk] = o;
        }
    }
}

// ---------- K5: out[r][v] = sum_d x[b,250+dn,d]*Wb[d][v] + b[v]
__global__ __launch_bounds__(256) void k_out(const float* x, const unsigned short* Wb,
                                             const float* bias, float* out) {
    int vt = blockIdx.x, rg = blockIdx.y, t = threadIdx.x;  // grid (10,50)
    __shared__ float xr[6][256];
    int r0 = rg * 6;                               // 150%6==0: never crosses b
    int b = r0 / 150, n0 = 250 + (r0 % 150);
    for (int i = t; i < 1536; i += 256) {
        int rr = i >> 8, dd = i & 255;
        xr[rr][dd] = x[(b * 400 + n0 + rr) * 256 + dd];
    }
    __syncthreads();
    int v = vt * 512 + t * 2;                      // 2 cols/thread, dword load
    if (v >= 5000) return;
    float acc[6][2];
#pragma unroll
    for (int rr = 0; rr < 6; ++rr) { acc[rr][0] = 0.f; acc[rr][1] = 0.f; }
    const unsigned short* Wp = Wb + v;
#pragma unroll 8
    for (int dd = 0; dd < 256; ++dd) {
        unsigned int wu = *reinterpret_cast<const unsigned int*>(Wp + dd * 5000);
        float w0 = bf2f_raw(wu & 0xFFFFu);
        float w1 = bf2f_raw(wu >> 16);
#pragma unroll
        for (int rr = 0; rr < 6; ++rr) {
            float xv = xr[rr][dd];
            acc[rr][0] += xv * w0;
            acc[rr][1] += xv * w1;
        }
    }
    float b0 = bias[v], b1 = bias[v + 1];
#pragma unroll
    for (int rr = 0; rr < 6; ++rr) {
        out[(r0 + rr) * 5000 + v]     = acc[rr][0] + b0;
        out[(r0 + rr) * 5000 + v + 1] = acc[rr][1] + b1;
    }
}

extern "C" void kernel_launch(void* const* d_in, const int* in_sizes, int n_in,
                              void* d_out, int out_size, void* d_ws, size_t ws_size,
                              hipStream_t stream) {
    const int*   enc   = (const int*)d_in[0];
    const int*   dec   = (const int*)d_in[1];
    const float* emb   = (const float*)d_in[3];
    const float* convw = (const float*)d_in[4];
    const float* convb = (const float*)d_in[5];
    const float* hstW  = (const float*)d_in[6];
    const float* hstb  = (const float*)d_in[7];
    const float* attW  = (const float*)d_in[15];
    const float* a1    = (const float*)d_in[16];
    const float* a2    = (const float*)d_in[17];
    const float* outW  = (const float*)d_in[18];
    const float* outb  = (const float*)d_in[19];
    float* out = (float*)d_out;

    char* ws = (char*)d_ws;
    float* T   = (float*)ws; ws += 5 * 128 * 128 * 4;
    float* xA  = (float*)ws; ws += 800 * 256 * 4;
    float* xB  = (float*)ws; ws += 800 * 256 * 4;
    float* Wh  = (float*)ws; ws += 16 * 400 * 32 * 4;
    float* f1  = (float*)ws; ws += 16 * 400 * 4;
    float* f2  = (float*)ws; ws += 16 * 400 * 4;
    unsigned short* Wb = (unsigned short*)ws; ws += 256 * 5000 * 2;

    k_prep<<<2628, 256, 0, stream>>>(emb, convw, T, outW, Wb);
    k_convhst<<<800, 256, 0, stream>>>(enc, dec, convb, T, hstW, hstb, xA);

    float* xin = xA;
    float* xo  = xB;
    for (int it = 0; it < 2; ++it) {
        k_wh<<<400, 256, 0, stream>>>(xin, attW, a1, a2, Wh, f1, f2);
        k_attn<<<dim3(25, 16), 256, 0, stream>>>(Wh, f1, f2, xo);
        float* tmp = xin; xin = xo; xo = tmp;
    }
    k_out<<<dim3(10, 50), 256, 0, stream>>>(xin, Wb, outb, out);
}

// Round 9
// 101.280 us; speedup vs baseline: 2.4506x; 1.0219x over previous
//
#include <hip/hip_runtime.h>
#include <hip/hip_bf16.h>
#include <math.h>

// Shapes: B=2, Le=250, Ld=150, N=400, Wl=16, Vin=128, E=64, F=128, K=5
//         H=8, hid=32, d=256, Vout=5000
// Inputs fp32, output fp32 (verified round 4). fixed_graph/dg_* dead:
// adj=clip(sigmoid+fixed,0,1) strictly positive => unmasked softmax.
// Round-8 lesson: k_attn's Whl LDS staging (57.6KB -> 68KB/block -> 2
// blocks/CU, 4-8 waves/CU) starved latency hiding; Wh[bh]=51.2KB is
// L2-resident and re-read by all tile-blocks => read it straight from L2
// (coalesced 1KB/wave pattern), LDS ~10KB, grid (50,16) for ~12 waves/CU.

__device__ __forceinline__ float bf2f_raw(unsigned int u) {
    union { unsigned int i; float f; } cv; cv.i = u << 16; return cv.f;
}
__device__ __forceinline__ unsigned short f2bf(float f) {
    __hip_bfloat16 h = __float2bfloat16(f);
    return *reinterpret_cast<unsigned short*>(&h);
}

// ---------- K0: fused { T[k5][v][f] = sum_e emb[v][e]*convw[f][e][k5] }
//                      { Wb = bf16(out_W) }
__global__ __launch_bounds__(256) void k_prep(const float* emb, const float* convw,
                                              float* T, const float* W,
                                              unsigned short* Wb) {
    int bid = blockIdx.x, t = threadIdx.x;
    if (bid < 128) {                               // table part: v = bid
        int v = bid;
        __shared__ float er[64];
        if (t < 64) er[t] = emb[v * 64 + t];
        __syncthreads();
        if (t < 128) {
            float acc[5] = {0.f, 0.f, 0.f, 0.f, 0.f};
            const float* w = convw + t * 320;      // convw[f][e][k5]
            for (int e = 0; e < 64; ++e) {
                float xe = er[e];
#pragma unroll
                for (int k = 0; k < 5; ++k) acc[k] += xe * w[e * 5 + k];
            }
#pragma unroll
            for (int k = 0; k < 5; ++k) T[(k * 128 + v) * 128 + t] = acc[k];
        }
    } else {                                       // w2b part: 512 elems/block
        int i0 = (bid - 128) * 512 + t * 2;        // 2500 blocks * 512 = 1.28M
        if (i0 < 256 * 5000) {
            float2 w2 = *reinterpret_cast<const float2*>(W + i0);
            unsigned int u = ((unsigned int)f2bf(w2.y) << 16) | f2bf(w2.x);
            *reinterpret_cast<unsigned int*>(Wb + i0) = u;
        }
    }
}

// ---------- K1: fused char-conv (+bias,relu,maxpool) and hst projection.
// 2 words/block: conv phase uses all 256 threads; hstW loads shared 2x.
__global__ __launch_bounds__(256) void k_convhst(const int* enc, const int* dec,
                                                 const float* convb, const float* T,
                                                 const float* hstW, const float* hstb,
                                                 float* x) {
    int w0 = blockIdx.x * 2, t = threadIdx.x;      // grid 400, block 256
    __shared__ int ids[2][16];
    __shared__ float xcl[2][128];
    if (t < 32) {
        int r = t >> 4, c = t & 15;
        int w = w0 + r;
        int b = w / 400, n = w % 400;
        ids[r][c] = (n < 250) ? enc[(b * 250 + n) * 16 + c]
                              : dec[(b * 150 + (n - 250)) * 16 + c];
    }
    __syncthreads();
    {
        int r = t >> 7, f = t & 127;               // word r, filter f
        float best = -1e30f;
        for (int p = 0; p < 16; ++p) {
            float s = 0.f;
#pragma unroll
            for (int k = 0; k < 5; ++k) {
                int q = p + k - 2;
                if (q >= 0 && q < 16) s += T[(k * 128 + ids[r][q]) * 128 + f];
            }
            best = fmaxf(best, s);
        }
        xcl[r][f] = fmaxf(best + convb[f], 0.f);
    }
    __syncthreads();
    float acc0 = hstb[t], acc1 = acc0;
    for (int c = 0; c < 128; ++c) {
        float wv = hstW[c * 256 + t];
        acc0 += xcl[0][c] * wv;
        acc1 += xcl[1][c] * wv;
    }
    x[w0 * 256 + t] = acc0;
    x[(w0 + 1) * 256 + t] = acc1;
}

// ---------- K3: Wh + fused f1/f2. 2 rows/block, attW streamed from L2.
__global__ __launch_bounds__(256) void k_wh(const float* x, const float* attW,
                                            const float* a1g, const float* a2g,
                                            float* Wh, float* f1, float* f2) {
    int blk = blockIdx.x, t = threadIdx.x;         // grid 400, block 256
    int w0 = blk * 2;                              // 2 rows, never crosses b
    int h = t >> 5, k = t & 31;
    __shared__ float xr[2][256];
    for (int i = t; i < 512; i += 256) xr[i >> 8][i & 255] = x[w0 * 256 + i];
    __syncthreads();
    float acc0 = 0.f, acc1 = 0.f;
    const float* Wp = attW + h * 8192 + k;         // per-wave: 2x128B segments/load
#pragma unroll 8
    for (int d = 0; d < 256; ++d) {
        float wv = Wp[d * 32];
        acc0 += xr[0][d] * wv;
        acc1 += xr[1][d] * wv;
    }
    float a1v = a1g[t], a2v = a2g[t];
    int b = w0 / 400;
    int bh = b * 8 + h;
    float accs[2] = {acc0, acc1};
#pragma unroll
    for (int rw = 0; rw < 2; ++rw) {
        int n = (w0 + rw) % 400;
        Wh[(bh * 400 + n) * 32 + k] = accs[rw];
        float v1 = accs[rw] * a1v, v2 = accs[rw] * a2v;
#pragma unroll
        for (int mm = 16; mm >= 1; mm >>= 1) {
            v1 += __shfl_xor(v1, mm, 64);
            v2 += __shfl_xor(v2, mm, 64);
        }
        if (k == 0) { f1[bh * 400 + n] = v1; f2[bh * 400 + n] = v2; }
    }
}

// ---------- K4: softmax + PV + elu. 8 rows/block, 4 rows per barrier-iter.
// No Wh staging: Wh[bh] (51.2KB) is L2-resident, P2 reads it coalesced
// (lanes (g,kq) -> 8 consecutive 128B rows = 1KB/wave). plT LDS reads are
// bank-disjoint broadcasts (4g mod 32). DPP xor 1/2/4 for g-reduce.
__global__ __launch_bounds__(256) void k_attn(const float* Wh, const float* f1g,
                                              const float* f2g, float* xout) {
    int tile = blockIdx.x, bh = blockIdx.y;        // grid (50, 16)
    int b = bh >> 3, h = bh & 7;
    int t = threadIdx.x;
    int n0 = tile * 8;
    __shared__ float f2l[400];
    __shared__ float4 plT[400];                    // p transposed: [m][4 rows]
    __shared__ float f1l[8];
    __shared__ float red[4][8][4][4];              // [wave][kq][rw][c]
    __shared__ float sred[2][4][4];
    __shared__ float wmax[4];

    float fm = -1e30f;
    for (int m = t; m < 400; m += 256) {
        float v = f2g[bh * 400 + m];
        f2l[m] = v;
        fm = fmaxf(fm, v);
    }
    if (t < 8) f1l[t] = f1g[bh * 400 + n0 + t];
#pragma unroll
    for (int mm = 32; mm >= 1; mm >>= 1) fm = fmaxf(fm, __shfl_xor(fm, mm, 64));
    if ((t & 63) == 0) wmax[t >> 6] = fm;
    __syncthreads();
    float fmax2 = fmaxf(fmaxf(wmax[0], wmax[1]), fmaxf(wmax[2], wmax[3]));

    int g = t & 7, kq = (t >> 3) & 7, wv = t >> 6;
    int gm = g + 8 * wv;                           // m-group 0..31
    const float4* WhG = (const float4*)(Wh + bh * 12800);
    for (int it = 0; it < 2; ++it) {
        // P1: all 4 rows' p at this thread's m -> plT[m]; denominator partials
        float f1a = f1l[it * 4 + 0], f1b = f1l[it * 4 + 1];
        float f1c = f1l[it * 4 + 2], f1d = f1l[it * 4 + 3];
        float rm0 = f1a + fmax2; rm0 = rm0 > 0.f ? rm0 : 0.2f * rm0;
        float rm1 = f1b + fmax2; rm1 = rm1 > 0.f ? rm1 : 0.2f * rm1;
        float rm2 = f1c + fmax2; rm2 = rm2 > 0.f ? rm2 : 0.2f * rm2;
        float rm3 = f1d + fmax2; rm3 = rm3 > 0.f ? rm3 : 0.2f * rm3;
        float ps0 = 0.f, ps1 = 0.f, ps2 = 0.f, ps3 = 0.f;
        for (int m = t; m < 400; m += 256) {
            float f2v = f2l[m];
            float e0 = f1a + f2v; e0 = e0 > 0.f ? e0 : 0.2f * e0;
            float e1 = f1b + f2v; e1 = e1 > 0.f ? e1 : 0.2f * e1;
            float e2 = f1c + f2v; e2 = e2 > 0.f ? e2 : 0.2f * e2;
            float e3 = f1d + f2v; e3 = e3 > 0.f ? e3 : 0.2f * e3;
            float4 pv;
            pv.x = __expf(e0 - rm0); ps0 += pv.x;
            pv.y = __expf(e1 - rm1); ps1 += pv.y;
            pv.z = __expf(e2 - rm2); ps2 += pv.z;
            pv.w = __expf(e3 - rm3); ps3 += pv.w;
            plT[m] = pv;
        }
        {
            float v0 = ps0, v1 = ps1, v2 = ps2, v3 = ps3;
#pragma unroll
            for (int mm = 32; mm >= 1; mm >>= 1) {
                v0 += __shfl_xor(v0, mm, 64);
                v1 += __shfl_xor(v1, mm, 64);
                v2 += __shfl_xor(v2, mm, 64);
                v3 += __shfl_xor(v3, mm, 64);
            }
            if ((t & 63) == 0) {
                int wq = t >> 6;
                sred[it & 1][0][wq] = v0; sred[it & 1][1][wq] = v1;
                sred[it & 1][2][wq] = v2; sred[it & 1][3][wq] = v3;
            }
        }
        __syncthreads();
        // P2: 4 rows x 4 cols; 1 global b128 (Wh, L2) + 1 LDS b128 (plT) per m
        float a[4][4];
#pragma unroll
        for (int rr = 0; rr < 4; ++rr)
#pragma unroll
            for (int c = 0; c < 4; ++c) a[rr][c] = 0.f;
#pragma unroll 4
        for (int m = gm; m < 400; m += 32) {
            float4 w4 = WhG[m * 8 + kq];
            float4 p4 = plT[m];
            a[0][0] += p4.x * w4.x; a[0][1] += p4.x * w4.y; a[0][2] += p4.x * w4.z; a[0][3] += p4.x * w4.w;
            a[1][0] += p4.y * w4.x; a[1][1] += p4.y * w4.y; a[1][2] += p4.y * w4.z; a[1][3] += p4.y * w4.w;
            a[2][0] += p4.z * w4.x; a[2][1] += p4.z * w4.y; a[2][2] += p4.z * w4.z; a[2][3] += p4.z * w4.w;
            a[3][0] += p4.w * w4.x; a[3][1] += p4.w * w4.y; a[3][2] += p4.w * w4.z; a[3][3] += p4.w * w4.w;
        }
        // reduce over g (lane bits 0..2 -> DPP, stays off the LDS pipe)
#pragma unroll
        for (int rr = 0; rr < 4; ++rr)
#pragma unroll
            for (int c = 0; c < 4; ++c) {
                float v = a[rr][c];
                v += __shfl_xor(v, 1, 64);
                v += __shfl_xor(v, 2, 64);
                v += __shfl_xor(v, 4, 64);
                a[rr][c] = v;
            }
        if (g == 0) {
#pragma unroll
            for (int rr = 0; rr < 4; ++rr)
#pragma unroll
                for (int c = 0; c < 4; ++c) red[wv][kq][rr][c] = a[rr][c];
        }
        __syncthreads();
        // P3: combine 4 wave-partials, normalize, elu, store
        if (t < 128) {
            int rw3 = t >> 5, kk = t & 31;
            int q3 = kk >> 2, c3 = kk & 3;
            float s = sred[it & 1][rw3][0] + sred[it & 1][rw3][1]
                    + sred[it & 1][rw3][2] + sred[it & 1][rw3][3];
            float o = (red[0][q3][rw3][c3] + red[1][q3][rw3][c3]
                     + red[2][q3][rw3][c3] + red[3][q3][rw3][c3]) / s;
            o = o > 0.f ? o : (__expf(o) - 1.f);   // elu
            int n = n0 + it * 4 + rw3;
            xout[(b * 400 + n) * 256 + h * 32 + kk] = o;
        }
    }
}

// ---------- K5: out[r][v] = sum_d x[b,250+dn,d]*Wb[d][v] + b[v]
__global__ __launch_bounds__(256) void k_out(const float* x, const unsigned short* Wb,
                                             const float* bias, float* out) {
    int vt = blockIdx.x, rg = blockIdx.y, t = threadIdx.x;  // grid (10,50)
    __shared__ float xr[6][256];
    int r0 = rg * 6;                               // 150%6==0: never crosses b
    int b = r0 / 150, n0 = 250 + (r0 % 150);
    for (int i = t; i < 1536; i += 256) {
        int rr = i >> 8, dd = i & 255;
        xr[rr][dd] = x[(b * 400 + n0 + rr) * 256 + dd];
    }
    __syncthreads();
    int v = vt * 512 + t * 2;                      // 2 cols/thread, dword load
    if (v >= 5000) return;
    float acc[6][2];
#pragma unroll
    for (int rr = 0; rr < 6; ++rr) { acc[rr][0] = 0.f; acc[rr][1] = 0.f; }
    const unsigned short* Wp = Wb + v;
#pragma unroll 8
    for (int dd = 0; dd < 256; ++dd) {
        unsigned int wu = *reinterpret_cast<const unsigned int*>(Wp + dd * 5000);
        float w0 = bf2f_raw(wu & 0xFFFFu);
        float w1 = bf2f_raw(wu >> 16);
#pragma unroll
        for (int rr = 0; rr < 6; ++rr) {
            float xv = xr[rr][dd];
            acc[rr][0] += xv * w0;
            acc[rr][1] += xv * w1;
        }
    }
    float b0 = bias[v], b1 = bias[v + 1];
#pragma unroll
    for (int rr = 0; rr < 6; ++rr) {
        out[(r0 + rr) * 5000 + v]     = acc[rr][0] + b0;
        out[(r0 + rr) * 5000 + v + 1] = acc[rr][1] + b1;
    }
}

extern "C" void kernel_launch(void* const* d_in, const int* in_sizes, int n_in,
                              void* d_out, int out_size, void* d_ws, size_t ws_size,
                              hipStream_t stream) {
    const int*   enc   = (const int*)d_in[0];
    const int*   dec   = (const int*)d_in[1];
    const float* emb   = (const float*)d_in[3];
    const float* convw = (const float*)d_in[4];
    const float* convb = (const float*)d_in[5];
    const float* hstW  = (const float*)d_in[6];
    const float* hstb  = (const float*)d_in[7];
    const float* attW  = (const float*)d_in[15];
    const float* a1    = (const float*)d_in[16];
    const float* a2    = (const float*)d_in[17];
    const float* outW  = (const float*)d_in[18];
    const float* outb  = (const float*)d_in[19];
    float* out = (float*)d_out;

    char* ws = (char*)d_ws;
    float* T   = (float*)ws; ws += 5 * 128 * 128 * 4;
    float* xA  = (float*)ws; ws += 800 * 256 * 4;
    float* xB  = (float*)ws; ws += 800 * 256 * 4;
    float* Wh  = (float*)ws; ws += 16 * 400 * 32 * 4;
    float* f1  = (float*)ws; ws += 16 * 400 * 4;
    float* f2  = (float*)ws; ws += 16 * 400 * 4;
    unsigned short* Wb = (unsigned short*)ws; ws += 256 * 5000 * 2;

    k_prep<<<2628, 256, 0, stream>>>(emb, convw, T, outW, Wb);
    k_convhst<<<400, 256, 0, stream>>>(enc, dec, convb, T, hstW, hstb, xA);

    float* xin = xA;
    float* xo  = xB;
    for (int it = 0; it < 2; ++it) {
        k_wh<<<400, 256, 0, stream>>>(xin, attW, a1, a2, Wh, f1, f2);
        k_attn<<<dim3(50, 16), 256, 0, stream>>>(Wh, f1, f2, xo);
        float* tmp = xin; xin = xo; xo = tmp;
    }
    k_out<<<dim3(10, 50), 256, 0, stream>>>(xin, Wb, outb, out);
}